// Round 3
// baseline (1072.958 us; speedup 1.0000x reference)
//
#include <hip/hip_runtime.h>
#include <cstdint>
#include <cstddef>

#define BB 16
#define NN 4096
#define CC 64
#define MM 1024
#define KK 64
#define HH 128
#define NEGV -1.0e30f

#define FTH 256   // fps active threads (4 waves, 1/SIMD) — R16's 8-wave refuted
#define FPT 16    // fps points per thread (FTH*FPT == NN)
#define NPROD 16  // producer blocks (one per batch)
#define GTOT 256  // total blocks: 1 per CU exactly (82KB LDS forces it)
#define PSTRIDE 32  // progress counter stride in u32 (128B: one cacheline/batch)

#define KC1 96    // layer-1 K dim padded (67 -> 96)
#define SA 104    // LDS stride of feat planes
#define SH 136    // LDS stride of h1 planes
#define HSTRIDE 41984  // per-half consumer LDS region

typedef __attribute__((ext_vector_type(8))) short bf16x8;
typedef __attribute__((ext_vector_type(4))) float f32x4;
typedef __attribute__((ext_vector_type(2))) float f32x2;

__device__ __forceinline__ unsigned int f2bf(float f) {
  unsigned int u = __float_as_uint(f);
  return (u + 0x7fffu + ((u >> 16) & 1u)) >> 16;
}
__device__ __forceinline__ void split2(float f, unsigned int& h, unsigned int& l) {
  h = f2bf(f);
  float hf = __uint_as_float(h << 16);
  l = f2bf(f - hf);
}

template <int CTRL, int RM>
__device__ __forceinline__ void dpp_max64(unsigned int& hi, unsigned int& lo) {
  unsigned int shi = (unsigned int)__builtin_amdgcn_update_dpp(
      (int)hi, (int)hi, CTRL, RM, 0xf, false);
  unsigned int slo = (unsigned int)__builtin_amdgcn_update_dpp(
      (int)lo, (int)lo, CTRL, RM, 0xf, false);
  unsigned long long cur = ((unsigned long long)hi << 32) | lo;
  unsigned long long oth = ((unsigned long long)shi << 32) | slo;
  if (oth > cur) { hi = shi; lo = slo; }
}

// ---------------------------------------------------------------------------
// pn: |p|^2 per point, exact order (x^2+y^2)+z^2, no FMA.
// ---------------------------------------------------------------------------
__global__ __launch_bounds__(256) void pn_kernel(const float* __restrict__ pos,
                                                 float* __restrict__ pn) {
#pragma clang fp contract(off)
  int i = blockIdx.x * 256 + threadIdx.x;
  if (i < BB * NN) {
    float x = pos[(size_t)i * 3 + 0];
    float y = pos[(size_t)i * 3 + 1];
    float z = pos[(size_t)i * 3 + 2];
    pn[i] = (x * x + y * y) + z * z;
  }
}

// ---------------------------------------------------------------------------
// Weight prep: transpose + pad + bf16 hi/lo split, B-fragment layout [n][k].
// ---------------------------------------------------------------------------
__global__ __launch_bounds__(128) void wprep_kernel(
    const float* __restrict__ W1, const float* __restrict__ W2,
    unsigned short* __restrict__ W1Th, unsigned short* __restrict__ W1Tl,
    unsigned short* __restrict__ W2Th, unsigned short* __restrict__ W2Tl) {
  const int n = blockIdx.x, t = threadIdx.x;
  if (t < KC1) {
    float v = (t < 67) ? W1[(size_t)t * HH + n] : 0.0f;
    unsigned int h, l; split2(v, h, l);
    W1Th[n * KC1 + t] = (unsigned short)h;
    W1Tl[n * KC1 + t] = (unsigned short)l;
  }
  {
    float v = W2[(size_t)t * HH + n];
    unsigned int h, l; split2(v, h, l);
    W2Th[n * HH + t] = (unsigned short)h;
    W2Tl[n * HH + t] = (unsigned short)l;
  }
}

// ---------------------------------------------------------------------------
// init: zero padded progress[16*32] + claim (ws is 0xAA-poisoned per launch)
// ---------------------------------------------------------------------------
__global__ void init_kernel(unsigned int* progress, unsigned int* claim) {
  int t = threadIdx.x;
  if (t < NPROD * PSTRIDE) progress[t] = 0u;
  if (t == NPROD * PSTRIDE) *claim = 0u;
}

// ---------------------------------------------------------------------------
// FUSED producer-consumer kernel, R17. Runtime == FPS critical path.
// R16 post-mortem: 8-wave producer REGRESSED (770->928): TLP doesn't help a
// barrier-locked loop; the sync itself got costlier. Revert to 4 waves.
// Ledger: issue-shaving (R15, -3%) and TLP (R16, -20%) both refuted ->
// the ~900cy/iter unmodeled term sits in the cross-wave handoff
// (ds_write -> lgkm drain -> s_barrier -> ds_read), i.e. barrier cost at
// 1 block/CU with wave0 always straggling (t0 bookkeeping + flush spikes).
// R17: REMOVE THE BARRIER from the loop.
//  (1) Seqlock LDS slot handshake: lane63 of each wave publishes
//      {tag=m, kh, kl, tag=m} (16B slot, parity double-buffered); keys
//      written first, lgkmcnt(0) drain, tags last. All waves spin on one
//      ds_read_b128 per slot until all 4 tags == m. Skew provably <= 1
//      iteration (a wave writes slot m+1 only after reading all slot-m's;
//      a slot-m write implies that wave consumed slot m-1) -> parity
//      reuse is race-free, no deadlock. Dual tag guards read tearing.
//  (2) Tournament-tree per-lane argmax (left-biased strict >): identical
//      selection semantics to the serial scan (first-max tie-break kept
//      via ~bi u64 key), chain ~-90cy, issue-neutral.
// Selections bit-identical -> absmax 0.015625 unchanged.
// ---------------------------------------------------------------------------
__global__ __launch_bounds__(512, 2) void fused_kernel(
    const float* __restrict__ pos, const float* __restrict__ x,
    const float* __restrict__ pn,
    float* __restrict__ pos_s_ws, float* __restrict__ pos_s_out,
    const unsigned short* __restrict__ W1Th, const unsigned short* __restrict__ W1Tl,
    const unsigned short* __restrict__ W2Th, const unsigned short* __restrict__ W2Tl,
    const float* __restrict__ b1, const float* __restrict__ b2,
    float* __restrict__ out,
    unsigned int* __restrict__ progress, unsigned int* __restrict__ claim) {
#pragma clang fp contract(off)
  __shared__ __attribute__((aligned(16))) unsigned char LBUF[83968];
  const int t = threadIdx.x;
  const int lane = t & 63;

  if (blockIdx.x < NPROD) {
    // =================== PRODUCER: FPS for batch b ===================
    if (t >= FTH) return;            // waves 4..7 exit; barriers below count live waves
    __builtin_amdgcn_s_setprio(3);
    const int wv = t >> 6;           // 0..3
    const int b = blockIdx.x;
    float4* P4 = (float4*)LBUF;                          // 65536 B
    float* SXa = (float*)(LBUF + 65536);                 // 4096 B
    float* SYa = (float*)(LBUF + 69632);                 // 4096 B
    float* SZa = (float*)(LBUF + 73728);                 // 4096 B
    uint4* slots = (uint4*)(LBUF + 77824);               // [2][4] seqlock slots
    const float* pb = pos + (size_t)b * NN * 3;
    f32x2 px[8], py[8], pz[8], dd[8];
#pragma unroll
    for (int j = 0; j < FPT; ++j) {
      int i = t + j * FTH;
      float xx = pb[i * 3 + 0], yy = pb[i * 3 + 1], zz = pb[i * 3 + 2];
      P4[i] = make_float4(xx, yy, zz, 0.0f);
      px[j >> 1][j & 1] = xx;
      py[j >> 1][j & 1] = yy;
      pz[j >> 1][j & 1] = zz;
      dd[j >> 1][j & 1] = 3.4028234663852886e38f;
    }
    if (t < 8) {
      uint4 z4; z4.x = 0u; z4.y = 0u; z4.z = 0u; z4.w = 0u;
      slots[t] = z4;
    }
    __syncthreads();
    float4 c4 = P4[0];
    float sx = c4.x, sy = c4.y, sz = c4.z;
    if (t == 0) { SXa[0] = sx; SYa[0] = sy; SZa[0] = sz; }

    for (int m = 1; m < MM; ++m) {
      f32x2 s2x = {sx, sx}, s2y = {sy, sy}, s2z = {sz, sz};
      float nv[16];
#pragma unroll
      for (int k = 0; k < 8; ++k) {
        f32x2 dx = px[k] - s2x, dy = py[k] - s2y, dz = pz[k] - s2z;
        f32x2 d2 = (dx * dx + dy * dy) + dz * dz;   // v_pk_*, no FMA (pragma)
        float n0 = fminf(dd[k][0], d2[0]);
        float n1 = fminf(dd[k][1], d2[1]);
        dd[k][0] = n0;
        dd[k][1] = n1;
        nv[2 * k] = n0;
        nv[2 * k + 1] = n1;
      }
      // left-biased tournament: winner == first-max of serial j-ascending scan
      float tv[8]; int ti[8];
#pragma unroll
      for (int k = 0; k < 8; ++k) {
        bool c = nv[2 * k + 1] > nv[2 * k];
        tv[k] = c ? nv[2 * k + 1] : nv[2 * k];
        ti[k] = c ? (2 * k + 1) : (2 * k);
      }
      float uv[4]; int ui[4];
#pragma unroll
      for (int k = 0; k < 4; ++k) {
        bool c = tv[2 * k + 1] > tv[2 * k];
        uv[k] = c ? tv[2 * k + 1] : tv[2 * k];
        ui[k] = c ? ti[2 * k + 1] : ti[2 * k];
      }
      float wv2[2]; int wi2[2];
#pragma unroll
      for (int k = 0; k < 2; ++k) {
        bool c = uv[2 * k + 1] > uv[2 * k];
        wv2[k] = c ? uv[2 * k + 1] : uv[2 * k];
        wi2[k] = c ? ui[2 * k + 1] : ui[2 * k];
      }
      bool cf = wv2[1] > wv2[0];
      float bv = cf ? wv2[1] : wv2[0];
      int bj = cf ? wi2[1] : wi2[0];
      int bi = t + (bj << 8);

      unsigned int kh = __float_as_uint(bv);
      unsigned int kl = ~(unsigned int)bi;
      dpp_max64<0x111, 0xf>(kh, kl);
      dpp_max64<0x112, 0xf>(kh, kl);
      dpp_max64<0x114, 0xf>(kh, kl);
      dpp_max64<0x118, 0xf>(kh, kl);
      dpp_max64<0x142, 0xa>(kh, kl);
      dpp_max64<0x143, 0xc>(kh, kl);
      const int p = m & 1;
      const unsigned int mu = (unsigned int)m;
      if (lane == 63) {
        volatile unsigned int* sw = (volatile unsigned int*)&slots[p * 4 + wv];
        sw[1] = kh;
        sw[2] = kl;
        asm volatile("s_waitcnt lgkmcnt(0)" ::: "memory");  // keys visible first
        sw[0] = mu;
        sw[3] = mu;
      }
      // spin until all 4 wave slots carry tag m (single b128 read per slot)
      uint4 c0, c1, c2, c3;
      for (;;) {
        __asm__ __volatile__("" ::: "memory");
        c0 = slots[p * 4 + 0];
        c1 = slots[p * 4 + 1];
        c2 = slots[p * 4 + 2];
        c3 = slots[p * 4 + 3];
        if (c0.x == mu && c0.w == mu && c1.x == mu && c1.w == mu &&
            c2.x == mu && c2.w == mu && c3.x == mu && c3.w == mu)
          break;
      }
      unsigned long long k0 = ((unsigned long long)c0.y << 32) | c0.z;
      unsigned long long k1 = ((unsigned long long)c1.y << 32) | c1.z;
      unsigned long long k2 = ((unsigned long long)c2.y << 32) | c2.z;
      unsigned long long k3 = ((unsigned long long)c3.y << 32) | c3.z;
      unsigned long long b01 = k0 > k1 ? k0 : k1;
      unsigned long long b23 = k2 > k3 ? k2 : k3;
      unsigned long long best = b01 > b23 ? b01 : b23;
      int fi = (int)(~(unsigned int)(best & 0xffffffffull));
      float4 w4 = P4[fi];
      sx = w4.x; sy = w4.y; sz = w4.z;
      if (t == 0) {
        SXa[m] = sx; SYa[m] = sy; SZa[m] = sz;
        if ((m & 15) == 15) {
          // issue relaxed agent stores; they retire during the next iterations.
          int base = m - 15;
          for (int j = 0; j < 16; ++j) {
            size_t o = ((size_t)b * MM + base + j) * 3;
            __hip_atomic_store(&pos_s_ws[o + 0], SXa[base + j], __ATOMIC_RELAXED, __HIP_MEMORY_SCOPE_AGENT);
            __hip_atomic_store(&pos_s_ws[o + 1], SYa[base + j], __ATOMIC_RELAXED, __HIP_MEMORY_SCOPE_AGENT);
            __hip_atomic_store(&pos_s_ws[o + 2], SZa[base + j], __ATOMIC_RELAXED, __HIP_MEMORY_SCOPE_AGENT);
          }
        } else if ((m & 15) == 0) {
          // hand-rolled release: prior pos_s stores complete at the coherence
          // point (vmcnt==0) before progress becomes visible.
          asm volatile("s_waitcnt vmcnt(0)" ::: "memory");
          __hip_atomic_store(&progress[b * PSTRIDE], mu,
                             __ATOMIC_RELAXED, __HIP_MEMORY_SCOPE_AGENT);
        }
      }
    }
    __syncthreads();   // SXa/SYa/SZa final values visible to all threads
    if (t == 0) {
      // final publish: last flush (m=1023) covered centers 1008..1023.
      asm volatile("s_waitcnt vmcnt(0)" ::: "memory");
      __hip_atomic_store(&progress[b * PSTRIDE], (unsigned int)MM,
                         __ATOMIC_RELAXED, __HIP_MEMORY_SCOPE_AGENT);
    }
    for (int i = t; i < MM; i += FTH) {
      size_t o = ((size_t)b * MM + i) * 3;
      pos_s_out[o + 0] = SXa[i];
      pos_s_out[o + 1] = SYa[i];
      pos_s_out[o + 2] = SZa[i];
    }
    return;
  }

  // ============ CONSUMER: two 4-wave pipelines (halves h=0,1) ============
  const int h = t >> 8;            // half id
  const int th = t & 255;          // half-local thread id
  const int wvh = (t >> 6) & 3;    // half-local wave id
  unsigned char* HB = LBUF + h * HSTRIDE;
  unsigned short* Ah = (unsigned short*)HB;
  unsigned short* Al = (unsigned short*)(HB + 64 * SA * 2);
  unsigned short* Hh = (unsigned short*)HB;
  unsigned short* Hl = (unsigned short*)(HB + 64 * SH * 2);
  int* nbr_s = (int*)(HB + 34816);
  unsigned long long* masksL = (unsigned long long*)(HB + 35072);
  int* prefixL = (int*)(HB + 35584);
  float* ctr = (float*)(HB + 35840);
  int* cntS = (int*)(HB + 35856);
  volatile int* cidShare = (int*)(LBUF + 83960);   // block-wide
  const int r = lane & 15, q = lane >> 4;
  const int wbase = wvh * 32;

  while (true) {
    if (t == 0) {
      unsigned int i = __hip_atomic_fetch_add(claim, 2u, __ATOMIC_RELAXED,
                                              __HIP_MEMORY_SCOPE_AGENT);
      *cidShare = (int)i;
    }
    __syncthreads();
    int i0 = *cidShare;
    if (i0 >= BB * MM) break;                      // uniform exit
    const int i = i0 + h;
    const bool active = (i < BB * MM);
    const int cid = active ? (((i & 15) << 10) | (i >> 4)) : 0;
    const int b = cid >> 10;
    const int m = cid & 1023;

    if (active && th < 64) {   // half's wave 0 polls production progress
      while ((int)__hip_atomic_load(&progress[b * PSTRIDE], __ATOMIC_RELAXED,
                                    __HIP_MEMORY_SCOPE_AGENT) <= m)
        __builtin_amdgcn_s_sleep(64);
    }
    if (active && th < 3)
      ctr[th] = __hip_atomic_load(&pos_s_ws[(size_t)cid * 3 + th],
                                  __ATOMIC_RELAXED, __HIP_MEMORY_SCOPE_AGENT);
    __syncthreads();

    // ---- ballq: 4-wave mask pass + prefix + compaction (per half) ----
    const float sx = ctr[0], sy = ctr[1], sz = ctr[2];
    const float sn = (sx * sx + sy * sy) + sz * sz;
    const float* pb = pos + (size_t)b * NN * 3;
    const float* pnb = pn + (size_t)b * NN;
    if (active) {
#pragma unroll
      for (int cc = 0; cc < 16; ++cc) {
        int c = (wvh << 4) + cc;
        int n = (c << 6) + lane;
        float xx = pb[n * 3 + 0], yy = pb[n * 3 + 1], zz = pb[n * 3 + 2];
        float dot = __builtin_fmaf(sz, zz, __builtin_fmaf(sy, yy, sx * xx));
        float d2 = (sn + pnb[n]) - 2.0f * dot;
        bool pred = d2 <= 0.04f;
        unsigned long long mask = __ballot(pred);
        if (lane == 0) masksL[c] = mask;
      }
    }
    __syncthreads();
    if (active && th < 64) {
      int pc = (int)__popcll(masksL[lane]);
      int incl = pc;
#pragma unroll
      for (int off = 1; off < 64; off <<= 1) {
        int o2 = __shfl_up(incl, off, 64);
        if (lane >= off) incl += o2;
      }
      prefixL[lane] = incl - pc;
      if (lane == 63) *cntS = incl < KK ? incl : KK;
    }
    __syncthreads();
    const int cnt = *cntS;
    if (active) {
#pragma unroll
      for (int cc = 0; cc < 16; ++cc) {
        int c = (wvh << 4) + cc;
        unsigned long long mk = masksL[c];
        bool pred = (mk >> lane) & 1ull;
        int slot = prefixL[c] + (int)__popcll(mk & ((1ull << lane) - 1ull));
        if (pred && slot < KK) nbr_s[slot] = (c << 6) + lane;
      }
    }
    __syncthreads();

    // ---- gather + hi/lo split into LDS feat planes ----
    if (active) {
      const int kn = th >> 2, p = th & 3;
      float vals[16];
      float d0 = 0.0f, d1 = 0.0f, d2v = 0.0f;
      if (kn < cnt) {
        int n = nbr_s[kn];
        const float* xp = x + ((size_t)b * NN + n) * CC + p * 16;
#pragma unroll
        for (int ii = 0; ii < 4; ++ii) {
          float4 v = ((const float4*)xp)[ii];
          vals[ii * 4 + 0] = v.x; vals[ii * 4 + 1] = v.y;
          vals[ii * 4 + 2] = v.z; vals[ii * 4 + 3] = v.w;
        }
        if (p == 0) {
          const float* pp = pos + ((size_t)b * NN + n) * 3;
          d0 = pp[0] - sx; d1 = pp[1] - sy; d2v = pp[2] - sz;
        }
      } else {
#pragma unroll
        for (int ii = 0; ii < 16; ++ii) vals[ii] = 0.0f;
      }
#pragma unroll
      for (int j = 0; j < 16; j += 2) {
        unsigned int h0, l0, h1, l1;
        split2(vals[j], h0, l0);
        split2(vals[j + 1], h1, l1);
        int c = p * 16 + j;
        *(unsigned int*)&Ah[kn * SA + c] = h0 | (h1 << 16);
        *(unsigned int*)&Al[kn * SA + c] = l0 | (l1 << 16);
      }
      if (p == 0) {
        unsigned int h0, l0, h1, l1, h2, l2;
        split2(d0, h0, l0); split2(d1, h1, l1); split2(d2v, h2, l2);
        *(unsigned int*)&Ah[kn * SA + 64] = h0 | (h1 << 16);
        *(unsigned int*)&Al[kn * SA + 64] = l0 | (l1 << 16);
        *(unsigned int*)&Ah[kn * SA + 66] = h2;
        *(unsigned int*)&Al[kn * SA + 66] = l2;
      } else if (p == 1) {
#pragma unroll
        for (int c = 68; c < 80; c += 2) {
          *(unsigned int*)&Ah[kn * SA + c] = 0u;
          *(unsigned int*)&Al[kn * SA + c] = 0u;
        }
      } else if (p == 2) {
#pragma unroll
        for (int c = 80; c < 96; c += 2) {
          *(unsigned int*)&Ah[kn * SA + c] = 0u;
          *(unsigned int*)&Al[kn * SA + c] = 0u;
        }
      }
    }
    __syncthreads();

    f32x4 acc[4][2];
#pragma unroll
    for (int mt = 0; mt < 4; ++mt)
#pragma unroll
      for (int nt = 0; nt < 2; ++nt) acc[mt][nt] = (f32x4)0.0f;

    // ---- layer 1 ----
    if (active) {
#pragma unroll
      for (int kc = 0; kc < 3; ++kc) {
        bf16x8 bh[2], bl[2];
#pragma unroll
        for (int nt = 0; nt < 2; ++nt) {
          int o = (wbase + nt * 16 + r) * KC1 + kc * 32 + q * 8;
          bh[nt] = *(const bf16x8*)(W1Th + o);
          bl[nt] = *(const bf16x8*)(W1Tl + o);
        }
#pragma unroll
        for (int mt = 0; mt < 4; ++mt) {
          int o = (mt * 16 + r) * SA + kc * 32 + q * 8;
          bf16x8 ah = *(const bf16x8*)&Ah[o];
          bf16x8 al = *(const bf16x8*)&Al[o];
#pragma unroll
          for (int nt = 0; nt < 2; ++nt) {
            acc[mt][nt] = __builtin_amdgcn_mfma_f32_16x16x32_bf16(ah, bh[nt], acc[mt][nt], 0, 0, 0);
            acc[mt][nt] = __builtin_amdgcn_mfma_f32_16x16x32_bf16(al, bh[nt], acc[mt][nt], 0, 0, 0);
            acc[mt][nt] = __builtin_amdgcn_mfma_f32_16x16x32_bf16(ah, bl[nt], acc[mt][nt], 0, 0, 0);
          }
        }
      }
    }
    __syncthreads();   // alias guard: A-plane reads done before H overwrite

    if (active) {
      float b1v[2] = { b1[wbase + r], b1[wbase + 16 + r] };
#pragma unroll
      for (int mt = 0; mt < 4; ++mt)
#pragma unroll
        for (int nt = 0; nt < 2; ++nt)
#pragma unroll
          for (int ii = 0; ii < 4; ++ii) {
            int mm = mt * 16 + q * 4 + ii;
            int n = wbase + nt * 16 + r;
            float v = fmaxf(acc[mt][nt][ii] + b1v[nt], 0.0f);
            unsigned int hh2, ll2; split2(v, hh2, ll2);
            Hh[mm * SH + n] = (unsigned short)hh2;
            Hl[mm * SH + n] = (unsigned short)ll2;
          }
    }
    __syncthreads();

    // ---- layer 2 + masked max ----
#pragma unroll
    for (int mt = 0; mt < 4; ++mt)
#pragma unroll
      for (int nt = 0; nt < 2; ++nt) acc[mt][nt] = (f32x4)0.0f;
    if (active) {
#pragma unroll
      for (int kc = 0; kc < 4; ++kc) {
        bf16x8 bh[2], bl[2];
#pragma unroll
        for (int nt = 0; nt < 2; ++nt) {
          int o = (wbase + nt * 16 + r) * HH + kc * 32 + q * 8;
          bh[nt] = *(const bf16x8*)(W2Th + o);
          bl[nt] = *(const bf16x8*)(W2Tl + o);
        }
#pragma unroll
        for (int mt = 0; mt < 4; ++mt) {
          int o = (mt * 16 + r) * SH + kc * 32 + q * 8;
          bf16x8 ah = *(const bf16x8*)&Hh[o];
          bf16x8 al = *(const bf16x8*)&Hl[o];
#pragma unroll
          for (int nt = 0; nt < 2; ++nt) {
            acc[mt][nt] = __builtin_amdgcn_mfma_f32_16x16x32_bf16(ah, bh[nt], acc[mt][nt], 0, 0, 0);
            acc[mt][nt] = __builtin_amdgcn_mfma_f32_16x16x32_bf16(al, bh[nt], acc[mt][nt], 0, 0, 0);
            acc[mt][nt] = __builtin_amdgcn_mfma_f32_16x16x32_bf16(ah, bl[nt], acc[mt][nt], 0, 0, 0);
          }
        }
      }
      float b2v[2] = { b2[wbase + r], b2[wbase + 16 + r] };
#pragma unroll
      for (int nt = 0; nt < 2; ++nt) {
        float vmax = NEGV;
#pragma unroll
        for (int mt = 0; mt < 4; ++mt)
#pragma unroll
          for (int ii = 0; ii < 4; ++ii) {
            int mm = mt * 16 + q * 4 + ii;
            float v = fmaxf(acc[mt][nt][ii] + b2v[nt], 0.0f);
            if (mm < cnt) vmax = fmaxf(vmax, v);
          }
        vmax = fmaxf(vmax, __shfl_xor(vmax, 16, 64));
        vmax = fmaxf(vmax, __shfl_xor(vmax, 32, 64));
        if (q == 0)
          out[(size_t)cid * HH + wbase + nt * 16 + r] = (cnt > 0) ? vmax : 0.0f;
      }
    }
    __syncthreads();   // LDS reuse guard before next center
  }
}

// ---------------------------------------------------------------------------
extern "C" void kernel_launch(void* const* d_in, const int* in_sizes, int n_in,
                              void* d_out, int out_size, void* d_ws, size_t ws_size,
                              hipStream_t stream) {
  const float* x   = (const float*)d_in[0];
  const float* pos = (const float*)d_in[1];
  const float* W1  = (const float*)d_in[2];
  const float* b1  = (const float*)d_in[3];
  const float* W2  = (const float*)d_in[4];
  const float* b2  = (const float*)d_in[5];
  float* out = (float*)d_out;
  float* pos_s_out = out + (size_t)BB * MM * HH;

  char* ws = (char*)d_ws;
  float* pos_s_ws = (float*)(ws);                          // 196608 B
  float* pn       = (float*)(ws + 196608);                 // 262144 B
  unsigned short* W1Th = (unsigned short*)(ws + 458752);   // 24576 B
  unsigned short* W1Tl = (unsigned short*)(ws + 483328);   // 24576 B
  unsigned short* W2Th = (unsigned short*)(ws + 507904);   // 32768 B
  unsigned short* W2Tl = (unsigned short*)(ws + 540672);   // 32768 B
  unsigned int* progress = (unsigned int*)(ws + 573440);   // 16*128 B
  unsigned int* claim    = (unsigned int*)(ws + 575488);   // 4 B

  wprep_kernel<<<HH, 128, 0, stream>>>(W1, W2, W1Th, W1Tl, W2Th, W2Tl);
  pn_kernel<<<(BB * NN) / 256, 256, 0, stream>>>(pos, pn);
  init_kernel<<<1, NPROD * PSTRIDE + 64, 0, stream>>>(progress, claim);
  fused_kernel<<<GTOT, 512, 0, stream>>>(pos, x, pn, pos_s_ws, pos_s_out,
                                         W1Th, W1Tl, W2Th, W2Tl, b1, b2, out,
                                         progress, claim);
}

// Round 4
// 767.540 us; speedup vs baseline: 1.3979x; 1.3979x over previous
//
#include <hip/hip_runtime.h>
#include <cstdint>
#include <cstddef>

#define BB 16
#define NN 4096
#define CC 64
#define MM 1024
#define KK 64
#define HH 128
#define NEGV -1.0e30f

#define FTH 256   // fps active threads (4 waves, 1/SIMD) — R16 8-wave refuted
#define FPT 16    // fps points per thread (FTH*FPT == NN)
#define NPROD 16  // producer blocks (one per batch)
#define GTOT 256  // total blocks: 1 per CU exactly (82KB LDS forces it)
#define PSTRIDE 32  // progress counter stride in u32 (128B: one cacheline/batch)

#define KC1 96    // layer-1 K dim padded (67 -> 96)
#define SA 104    // LDS stride of feat planes
#define SH 136    // LDS stride of h1 planes
#define HSTRIDE 41984  // per-half consumer LDS region

typedef __attribute__((ext_vector_type(8))) short bf16x8;
typedef __attribute__((ext_vector_type(4))) float f32x4;
typedef __attribute__((ext_vector_type(2))) float f32x2;

__device__ __forceinline__ unsigned int f2bf(float f) {
  unsigned int u = __float_as_uint(f);
  return (u + 0x7fffu + ((u >> 16) & 1u)) >> 16;
}
__device__ __forceinline__ void split2(float f, unsigned int& h, unsigned int& l) {
  h = f2bf(f);
  float hf = __uint_as_float(h << 16);
  l = f2bf(f - hf);
}

template <int CTRL, int RM>
__device__ __forceinline__ void dpp_max64(unsigned int& hi, unsigned int& lo) {
  unsigned int shi = (unsigned int)__builtin_amdgcn_update_dpp(
      (int)hi, (int)hi, CTRL, RM, 0xf, false);
  unsigned int slo = (unsigned int)__builtin_amdgcn_update_dpp(
      (int)lo, (int)lo, CTRL, RM, 0xf, false);
  unsigned long long cur = ((unsigned long long)hi << 32) | lo;
  unsigned long long oth = ((unsigned long long)shi << 32) | slo;
  if (oth > cur) { hi = shi; lo = slo; }
}

// ---------------------------------------------------------------------------
// Weight prep (transpose + pad + bf16 hi/lo split) + progress/claim init
// (block 0). Runs as the single pre-dispatch; stream order guarantees both
// complete before fused_kernel starts. pn_kernel deleted (R18): consumers
// compute |p|^2 inline — bit-identical expression, they're 8x oversupplied.
// ---------------------------------------------------------------------------
__global__ __launch_bounds__(128) void wprep_kernel(
    const float* __restrict__ W1, const float* __restrict__ W2,
    unsigned short* __restrict__ W1Th, unsigned short* __restrict__ W1Tl,
    unsigned short* __restrict__ W2Th, unsigned short* __restrict__ W2Tl,
    unsigned int* __restrict__ progress, unsigned int* __restrict__ claim) {
  const int n = blockIdx.x, t = threadIdx.x;
  if (n == 0) {
    for (int j = t; j < NPROD * PSTRIDE; j += 128) progress[j] = 0u;
    if (t == 0) *claim = 0u;
  }
  if (t < KC1) {
    float v = (t < 67) ? W1[(size_t)t * HH + n] : 0.0f;
    unsigned int h, l; split2(v, h, l);
    W1Th[n * KC1 + t] = (unsigned short)h;
    W1Tl[n * KC1 + t] = (unsigned short)l;
  }
  {
    float v = W2[(size_t)t * HH + n];
    unsigned int h, l; split2(v, h, l);
    W2Th[n * HH + t] = (unsigned short)h;
    W2Tl[n * HH + t] = (unsigned short)l;
  }
}

// ---------------------------------------------------------------------------
// FUSED producer-consumer kernel, R18. Runtime == FPS critical path.
// R17 post-mortem: seqlock spin REGRESSED (770->1036): s_barrier's HW wakeup
// beats coarse LDS polling; tournament + handshake were numerically correct.
// Revised model: at 1 wave/SIMD, dependent-op LATENCY (~8cy) prices every
// serial chain; R15's 1806cy/iter ~= phaseA(260 issue) + serial argmax(~380)
// + DPP chain + u64 tree + 2 LDS round trips + barrier. R18 = R15 structure
// (barrier restored) + chain surgery:
//  (1) tournament-tree argmax (left-biased strict >, proven R17): 16-step
//      serial select chain -> 5 levels. First-max semantics preserved.
//  (2) flush parallelized: lanes 0-15 of wave0 store one center each
//      (3 stores/lane) instead of 96 serial instrs on lane0 (the barrier
//      straggler). Release ordering unchanged (vmcnt(0) drains the whole
//      wave's stores, incl. lanes 1-15).
//  (3) pn_kernel / init_kernel launches deleted (inline pn; init in wprep).
// Selections bit-identical -> absmax 0.015625 unchanged.
// ---------------------------------------------------------------------------
__global__ __launch_bounds__(512, 2) void fused_kernel(
    const float* __restrict__ pos, const float* __restrict__ x,
    float* __restrict__ pos_s_ws, float* __restrict__ pos_s_out,
    const unsigned short* __restrict__ W1Th, const unsigned short* __restrict__ W1Tl,
    const unsigned short* __restrict__ W2Th, const unsigned short* __restrict__ W2Tl,
    const float* __restrict__ b1, const float* __restrict__ b2,
    float* __restrict__ out,
    unsigned int* __restrict__ progress, unsigned int* __restrict__ claim) {
#pragma clang fp contract(off)
  __shared__ __attribute__((aligned(16))) unsigned char LBUF[83968];
  const int t = threadIdx.x;
  const int lane = t & 63;

  if (blockIdx.x < NPROD) {
    // =================== PRODUCER: FPS for batch b ===================
    if (t >= FTH) return;            // waves 4..7 exit; barrier counts live waves
    __builtin_amdgcn_s_setprio(3);
    const int wv = t >> 6;           // 0..3
    const int b = blockIdx.x;
    float4* P4 = (float4*)LBUF;                          // 65536 B
    float* SXa = (float*)(LBUF + 65536);                 // 4096 B
    float* SYa = (float*)(LBUF + 69632);                 // 4096 B
    float* SZa = (float*)(LBUF + 73728);                 // 4096 B
    unsigned long long* cand = (unsigned long long*)(LBUF + 77824); // [2][4]
    const float* pb = pos + (size_t)b * NN * 3;
    f32x2 px[8], py[8], pz[8], dd[8];
#pragma unroll
    for (int j = 0; j < FPT; ++j) {
      int i = t + j * FTH;
      float xx = pb[i * 3 + 0], yy = pb[i * 3 + 1], zz = pb[i * 3 + 2];
      P4[i] = make_float4(xx, yy, zz, 0.0f);
      px[j >> 1][j & 1] = xx;
      py[j >> 1][j & 1] = yy;
      pz[j >> 1][j & 1] = zz;
      dd[j >> 1][j & 1] = 3.4028234663852886e38f;
    }
    __syncthreads();
    float4 c4 = P4[0];
    float sx = c4.x, sy = c4.y, sz = c4.z;
    if (t == 0) { SXa[0] = sx; SYa[0] = sy; SZa[0] = sz; }

    for (int m = 1; m < MM; ++m) {
      f32x2 s2x = {sx, sx}, s2y = {sy, sy}, s2z = {sz, sz};
      float nv[16];
#pragma unroll
      for (int k = 0; k < 8; ++k) {
        f32x2 dx = px[k] - s2x, dy = py[k] - s2y, dz = pz[k] - s2z;
        f32x2 d2 = (dx * dx + dy * dy) + dz * dz;   // v_pk_*, no FMA (pragma)
        float n0 = fminf(dd[k][0], d2[0]);
        float n1 = fminf(dd[k][1], d2[1]);
        dd[k][0] = n0;
        dd[k][1] = n1;
        nv[2 * k] = n0;
        nv[2 * k + 1] = n1;
      }
      // left-biased tournament: winner == first-max of serial j-ascending scan
      float tv[8]; int ti[8];
#pragma unroll
      for (int k = 0; k < 8; ++k) {
        bool c = nv[2 * k + 1] > nv[2 * k];
        tv[k] = c ? nv[2 * k + 1] : nv[2 * k];
        ti[k] = c ? (2 * k + 1) : (2 * k);
      }
      float uv[4]; int ui[4];
#pragma unroll
      for (int k = 0; k < 4; ++k) {
        bool c = tv[2 * k + 1] > tv[2 * k];
        uv[k] = c ? tv[2 * k + 1] : tv[2 * k];
        ui[k] = c ? ti[2 * k + 1] : ti[2 * k];
      }
      float wv2[2]; int wi2[2];
#pragma unroll
      for (int k = 0; k < 2; ++k) {
        bool c = uv[2 * k + 1] > uv[2 * k];
        wv2[k] = c ? uv[2 * k + 1] : uv[2 * k];
        wi2[k] = c ? ui[2 * k + 1] : ui[2 * k];
      }
      bool cf = wv2[1] > wv2[0];
      float bv = cf ? wv2[1] : wv2[0];
      int bj = cf ? wi2[1] : wi2[0];
      int bi = t + (bj << 8);

      unsigned int kh = __float_as_uint(bv);
      unsigned int kl = ~(unsigned int)bi;
      dpp_max64<0x111, 0xf>(kh, kl);
      dpp_max64<0x112, 0xf>(kh, kl);
      dpp_max64<0x114, 0xf>(kh, kl);
      dpp_max64<0x118, 0xf>(kh, kl);
      dpp_max64<0x142, 0xa>(kh, kl);
      dpp_max64<0x143, 0xc>(kh, kl);
      if (lane == 63)
        cand[(m & 1) * 4 + wv] = ((unsigned long long)kh << 32) | kl;
      __syncthreads();
      unsigned long long best = cand[(m & 1) * 4 + 0];
#pragma unroll
      for (int w = 1; w < 4; ++w) {
        unsigned long long ok = cand[(m & 1) * 4 + w];
        best = ok > best ? ok : best;
      }
      int fi = (int)(~(unsigned int)(best & 0xffffffffull));
      float4 w4 = P4[fi];
      sx = w4.x; sy = w4.y; sz = w4.z;
      if (t == 0) { SXa[m] = sx; SYa[m] = sy; SZa[m] = sz; }
      if ((m & 15) == 15) {
        // parallel flush: lanes 0..15 of wave0 each publish one center.
        // SXa[m] was just written by lane0 of the SAME wave (in-order DS).
        if (t < 16) {
          int idx = (m - 15) + t;
          float fx = SXa[idx], fy = SYa[idx], fz = SZa[idx];
          size_t o = ((size_t)b * MM + idx) * 3;
          __hip_atomic_store(&pos_s_ws[o + 0], fx, __ATOMIC_RELAXED, __HIP_MEMORY_SCOPE_AGENT);
          __hip_atomic_store(&pos_s_ws[o + 1], fy, __ATOMIC_RELAXED, __HIP_MEMORY_SCOPE_AGENT);
          __hip_atomic_store(&pos_s_ws[o + 2], fz, __ATOMIC_RELAXED, __HIP_MEMORY_SCOPE_AGENT);
        }
      } else if ((m & 15) == 0 && t == 0) {
        // hand-rolled release: prior flush stores (all 16 lanes of wave0,
        // tracked by the wave's vmcnt) complete at the coherence point
        // before progress becomes visible.
        asm volatile("s_waitcnt vmcnt(0)" ::: "memory");
        __hip_atomic_store(&progress[b * PSTRIDE], (unsigned int)m,
                           __ATOMIC_RELAXED, __HIP_MEMORY_SCOPE_AGENT);
      }
    }
    __syncthreads();   // SXa/SYa/SZa final values visible to all threads
    if (t == 0) {
      // final publish: last flush (m=1023) covered centers 1008..1023.
      asm volatile("s_waitcnt vmcnt(0)" ::: "memory");
      __hip_atomic_store(&progress[b * PSTRIDE], (unsigned int)MM,
                         __ATOMIC_RELAXED, __HIP_MEMORY_SCOPE_AGENT);
    }
    for (int i = t; i < MM; i += FTH) {
      size_t o = ((size_t)b * MM + i) * 3;
      pos_s_out[o + 0] = SXa[i];
      pos_s_out[o + 1] = SYa[i];
      pos_s_out[o + 2] = SZa[i];
    }
    return;
  }

  // ============ CONSUMER: two 4-wave pipelines (halves h=0,1) ============
  const int h = t >> 8;            // half id
  const int th = t & 255;          // half-local thread id
  const int wvh = (t >> 6) & 3;    // half-local wave id
  unsigned char* HB = LBUF + h * HSTRIDE;
  unsigned short* Ah = (unsigned short*)HB;
  unsigned short* Al = (unsigned short*)(HB + 64 * SA * 2);
  unsigned short* Hh = (unsigned short*)HB;
  unsigned short* Hl = (unsigned short*)(HB + 64 * SH * 2);
  int* nbr_s = (int*)(HB + 34816);
  unsigned long long* masksL = (unsigned long long*)(HB + 35072);
  int* prefixL = (int*)(HB + 35584);
  float* ctr = (float*)(HB + 35840);
  int* cntS = (int*)(HB + 35856);
  volatile int* cidShare = (int*)(LBUF + 83960);   // block-wide
  const int r = lane & 15, q = lane >> 4;
  const int wbase = wvh * 32;

  while (true) {
    if (t == 0) {
      unsigned int i = __hip_atomic_fetch_add(claim, 2u, __ATOMIC_RELAXED,
                                              __HIP_MEMORY_SCOPE_AGENT);
      *cidShare = (int)i;
    }
    __syncthreads();
    int i0 = *cidShare;
    if (i0 >= BB * MM) break;                      // uniform exit
    const int i = i0 + h;
    const bool active = (i < BB * MM);
    const int cid = active ? (((i & 15) << 10) | (i >> 4)) : 0;
    const int b = cid >> 10;
    const int m = cid & 1023;

    if (active && th < 64) {   // half's wave 0 polls production progress
      while ((int)__hip_atomic_load(&progress[b * PSTRIDE], __ATOMIC_RELAXED,
                                    __HIP_MEMORY_SCOPE_AGENT) <= m)
        __builtin_amdgcn_s_sleep(64);
    }
    if (active && th < 3)
      ctr[th] = __hip_atomic_load(&pos_s_ws[(size_t)cid * 3 + th],
                                  __ATOMIC_RELAXED, __HIP_MEMORY_SCOPE_AGENT);
    __syncthreads();

    // ---- ballq: 4-wave mask pass + prefix + compaction (per half) ----
    const float sx = ctr[0], sy = ctr[1], sz = ctr[2];
    const float sn = (sx * sx + sy * sy) + sz * sz;
    const float* pb = pos + (size_t)b * NN * 3;
    if (active) {
#pragma unroll
      for (int cc = 0; cc < 16; ++cc) {
        int c = (wvh << 4) + cc;
        int n = (c << 6) + lane;
        float xx = pb[n * 3 + 0], yy = pb[n * 3 + 1], zz = pb[n * 3 + 2];
        float pnn = (xx * xx + yy * yy) + zz * zz;  // == old pn[n] bitwise
        float dot = __builtin_fmaf(sz, zz, __builtin_fmaf(sy, yy, sx * xx));
        float d2 = (sn + pnn) - 2.0f * dot;
        bool pred = d2 <= 0.04f;
        unsigned long long mask = __ballot(pred);
        if (lane == 0) masksL[c] = mask;
      }
    }
    __syncthreads();
    if (active && th < 64) {
      int pc = (int)__popcll(masksL[lane]);
      int incl = pc;
#pragma unroll
      for (int off = 1; off < 64; off <<= 1) {
        int o2 = __shfl_up(incl, off, 64);
        if (lane >= off) incl += o2;
      }
      prefixL[lane] = incl - pc;
      if (lane == 63) *cntS = incl < KK ? incl : KK;
    }
    __syncthreads();
    const int cnt = *cntS;
    if (active) {
#pragma unroll
      for (int cc = 0; cc < 16; ++cc) {
        int c = (wvh << 4) + cc;
        unsigned long long mk = masksL[c];
        bool pred = (mk >> lane) & 1ull;
        int slot = prefixL[c] + (int)__popcll(mk & ((1ull << lane) - 1ull));
        if (pred && slot < KK) nbr_s[slot] = (c << 6) + lane;
      }
    }
    __syncthreads();

    // ---- gather + hi/lo split into LDS feat planes ----
    if (active) {
      const int kn = th >> 2, p = th & 3;
      float vals[16];
      float d0 = 0.0f, d1 = 0.0f, d2v = 0.0f;
      if (kn < cnt) {
        int n = nbr_s[kn];
        const float* xp = x + ((size_t)b * NN + n) * CC + p * 16;
#pragma unroll
        for (int ii = 0; ii < 4; ++ii) {
          float4 v = ((const float4*)xp)[ii];
          vals[ii * 4 + 0] = v.x; vals[ii * 4 + 1] = v.y;
          vals[ii * 4 + 2] = v.z; vals[ii * 4 + 3] = v.w;
        }
        if (p == 0) {
          const float* pp = pos + ((size_t)b * NN + n) * 3;
          d0 = pp[0] - sx; d1 = pp[1] - sy; d2v = pp[2] - sz;
        }
      } else {
#pragma unroll
        for (int ii = 0; ii < 16; ++ii) vals[ii] = 0.0f;
      }
#pragma unroll
      for (int j = 0; j < 16; j += 2) {
        unsigned int h0, l0, h1, l1;
        split2(vals[j], h0, l0);
        split2(vals[j + 1], h1, l1);
        int c = p * 16 + j;
        *(unsigned int*)&Ah[kn * SA + c] = h0 | (h1 << 16);
        *(unsigned int*)&Al[kn * SA + c] = l0 | (l1 << 16);
      }
      if (p == 0) {
        unsigned int h0, l0, h1, l1, h2, l2;
        split2(d0, h0, l0); split2(d1, h1, l1); split2(d2v, h2, l2);
        *(unsigned int*)&Ah[kn * SA + 64] = h0 | (h1 << 16);
        *(unsigned int*)&Al[kn * SA + 64] = l0 | (l1 << 16);
        *(unsigned int*)&Ah[kn * SA + 66] = h2;
        *(unsigned int*)&Al[kn * SA + 66] = l2;
      } else if (p == 1) {
#pragma unroll
        for (int c = 68; c < 80; c += 2) {
          *(unsigned int*)&Ah[kn * SA + c] = 0u;
          *(unsigned int*)&Al[kn * SA + c] = 0u;
        }
      } else if (p == 2) {
#pragma unroll
        for (int c = 80; c < 96; c += 2) {
          *(unsigned int*)&Ah[kn * SA + c] = 0u;
          *(unsigned int*)&Al[kn * SA + c] = 0u;
        }
      }
    }
    __syncthreads();

    f32x4 acc[4][2];
#pragma unroll
    for (int mt = 0; mt < 4; ++mt)
#pragma unroll
      for (int nt = 0; nt < 2; ++nt) acc[mt][nt] = (f32x4)0.0f;

    // ---- layer 1 ----
    if (active) {
#pragma unroll
      for (int kc = 0; kc < 3; ++kc) {
        bf16x8 bh[2], bl[2];
#pragma unroll
        for (int nt = 0; nt < 2; ++nt) {
          int o = (wbase + nt * 16 + r) * KC1 + kc * 32 + q * 8;
          bh[nt] = *(const bf16x8*)(W1Th + o);
          bl[nt] = *(const bf16x8*)(W1Tl + o);
        }
#pragma unroll
        for (int mt = 0; mt < 4; ++mt) {
          int o = (mt * 16 + r) * SA + kc * 32 + q * 8;
          bf16x8 ah = *(const bf16x8*)&Ah[o];
          bf16x8 al = *(const bf16x8*)&Al[o];
#pragma unroll
          for (int nt = 0; nt < 2; ++nt) {
            acc[mt][nt] = __builtin_amdgcn_mfma_f32_16x16x32_bf16(ah, bh[nt], acc[mt][nt], 0, 0, 0);
            acc[mt][nt] = __builtin_amdgcn_mfma_f32_16x16x32_bf16(al, bh[nt], acc[mt][nt], 0, 0, 0);
            acc[mt][nt] = __builtin_amdgcn_mfma_f32_16x16x32_bf16(ah, bl[nt], acc[mt][nt], 0, 0, 0);
          }
        }
      }
    }
    __syncthreads();   // alias guard: A-plane reads done before H overwrite

    if (active) {
      float b1v[2] = { b1[wbase + r], b1[wbase + 16 + r] };
#pragma unroll
      for (int mt = 0; mt < 4; ++mt)
#pragma unroll
        for (int nt = 0; nt < 2; ++nt)
#pragma unroll
          for (int ii = 0; ii < 4; ++ii) {
            int mm = mt * 16 + q * 4 + ii;
            int n = wbase + nt * 16 + r;
            float v = fmaxf(acc[mt][nt][ii] + b1v[nt], 0.0f);
            unsigned int hh2, ll2; split2(v, hh2, ll2);
            Hh[mm * SH + n] = (unsigned short)hh2;
            Hl[mm * SH + n] = (unsigned short)ll2;
          }
    }
    __syncthreads();

    // ---- layer 2 + masked max ----
#pragma unroll
    for (int mt = 0; mt < 4; ++mt)
#pragma unroll
      for (int nt = 0; nt < 2; ++nt) acc[mt][nt] = (f32x4)0.0f;
    if (active) {
#pragma unroll
      for (int kc = 0; kc < 4; ++kc) {
        bf16x8 bh[2], bl[2];
#pragma unroll
        for (int nt = 0; nt < 2; ++nt) {
          int o = (wbase + nt * 16 + r) * HH + kc * 32 + q * 8;
          bh[nt] = *(const bf16x8*)(W2Th + o);
          bl[nt] = *(const bf16x8*)(W2Tl + o);
        }
#pragma unroll
        for (int mt = 0; mt < 4; ++mt) {
          int o = (mt * 16 + r) * SH + kc * 32 + q * 8;
          bf16x8 ah = *(const bf16x8*)&Hh[o];
          bf16x8 al = *(const bf16x8*)&Hl[o];
#pragma unroll
          for (int nt = 0; nt < 2; ++nt) {
            acc[mt][nt] = __builtin_amdgcn_mfma_f32_16x16x32_bf16(ah, bh[nt], acc[mt][nt], 0, 0, 0);
            acc[mt][nt] = __builtin_amdgcn_mfma_f32_16x16x32_bf16(al, bh[nt], acc[mt][nt], 0, 0, 0);
            acc[mt][nt] = __builtin_amdgcn_mfma_f32_16x16x32_bf16(ah, bl[nt], acc[mt][nt], 0, 0, 0);
          }
        }
      }
      float b2v[2] = { b2[wbase + r], b2[wbase + 16 + r] };
#pragma unroll
      for (int nt = 0; nt < 2; ++nt) {
        float vmax = NEGV;
#pragma unroll
        for (int mt = 0; mt < 4; ++mt)
#pragma unroll
          for (int ii = 0; ii < 4; ++ii) {
            int mm = mt * 16 + q * 4 + ii;
            float v = fmaxf(acc[mt][nt][ii] + b2v[nt], 0.0f);
            if (mm < cnt) vmax = fmaxf(vmax, v);
          }
        vmax = fmaxf(vmax, __shfl_xor(vmax, 16, 64));
        vmax = fmaxf(vmax, __shfl_xor(vmax, 32, 64));
        if (q == 0)
          out[(size_t)cid * HH + wbase + nt * 16 + r] = (cnt > 0) ? vmax : 0.0f;
      }
    }
    __syncthreads();   // LDS reuse guard before next center
  }
}

// ---------------------------------------------------------------------------
extern "C" void kernel_launch(void* const* d_in, const int* in_sizes, int n_in,
                              void* d_out, int out_size, void* d_ws, size_t ws_size,
                              hipStream_t stream) {
  const float* x   = (const float*)d_in[0];
  const float* pos = (const float*)d_in[1];
  const float* W1  = (const float*)d_in[2];
  const float* b1  = (const float*)d_in[3];
  const float* W2  = (const float*)d_in[4];
  const float* b2  = (const float*)d_in[5];
  float* out = (float*)d_out;
  float* pos_s_out = out + (size_t)BB * MM * HH;

  char* ws = (char*)d_ws;
  float* pos_s_ws = (float*)(ws);                          // 196608 B
  unsigned short* W1Th = (unsigned short*)(ws + 458752);   // 24576 B
  unsigned short* W1Tl = (unsigned short*)(ws + 483328);   // 24576 B
  unsigned short* W2Th = (unsigned short*)(ws + 507904);   // 32768 B
  unsigned short* W2Tl = (unsigned short*)(ws + 540672);   // 32768 B
  unsigned int* progress = (unsigned int*)(ws + 573440);   // 16*128 B
  unsigned int* claim    = (unsigned int*)(ws + 575488);   // 4 B

  wprep_kernel<<<HH, 128, 0, stream>>>(W1, W2, W1Th, W1Tl, W2Th, W2Tl,
                                       progress, claim);
  fused_kernel<<<GTOT, 512, 0, stream>>>(pos, x, pos_s_ws, pos_s_out,
                                         W1Th, W1Tl, W2Th, W2Tl, b1, b2, out,
                                         progress, claim);
}